// Round 7
// baseline (86.142 us; speedup 1.0000x reference)
//
#include <hip/hip_runtime.h>
#include <math.h>

// Problem shape (fixed by harness setup_inputs): B=8, N=M=4096, D=3, fp32.
#define B_SZ 8
#define N_SZ 4096
#define M_SZ 4096
#define NQ (B_SZ * N_SZ)            // 32768 queries per direction
#define TOT (2 * NQ)                // 65536 total queries

#define THREADS 256
#define QPT 16                      // queries per thread (4096 = one cloud / block-row)
#define JTILE 128                   // targets per strip
#define NJT (M_SZ / JTILE)          // 32 strips (= partial rows)
#define PAIRS_PER_CLOUD (M_SZ / 2)  // 2048
#define NBLK2 (TOT / 256)           // 256 phase-2 blocks

typedef float f32x2 __attribute__((ext_vector_type(2)));

// ws layout (floats):
//   part[g * TOT + q] : g in [0,NJT)            -> 8 MB
//   bsum[NBLK2]       : at NJT*TOT              -> 1 KB
//   TT    : packed targets, 2*B*PAIRS_PER_CLOUD pairs * 2 float4 -> 1 MB
// Every slot of part/bsum/TT is rewritten each call; harness 0xAA poison
// needs no clearing. No atomics anywhere.

// Prep: pack each target cloud pair-interleaved: per pair p of cloud
// (dir,b): [x0,x1,y0,y1][z0,z1,h0,h1], h = |t|^2/2. One thread per pair.
__global__ __launch_bounds__(256)
void chamfer_pack_kernel(const float* __restrict__ pred,
                         const float* __restrict__ tgt,
                         float4* __restrict__ TT)
{
    const int pid = blockIdx.x * 256 + threadIdx.x;    // [0, 2*B*2048)
    const int lp  = pid & (PAIRS_PER_CLOUD - 1);
    const int cb  = pid >> 11;                         // dir*B + b
    const int dir = cb >> 3;
    const int b   = cb & (B_SZ - 1);
    // dir 0: queries=pred, targets=tgt ; dir 1: swapped.
    const float* Db = (dir == 0) ? (tgt  + (size_t)b * M_SZ * 3)
                                 : (pred + (size_t)b * N_SZ * 3);
    const float* s = Db + (size_t)(2 * lp) * 3;
    float x0 = s[0], y0 = s[1], z0 = s[2];
    float x1 = s[3], y1 = s[4], z1 = s[5];
    float h0 = 0.5f * (x0 * x0 + y0 * y0 + z0 * z0);
    float h1 = 0.5f * (x1 * x1 + y1 * y1 + z1 * z1);
    TT[2 * pid]     = make_float4(x0, x1, y0, y1);
    TT[2 * pid + 1] = make_float4(z0, z1, h0, h1);
}

// score(q,t) = |t|^2/2 - q.t ; partial = min score + |q|^2/2 = min|q-t|^2/2.
// NO LDS, NO barrier: each block streams its 2 KB packed strip straight from
// global (wave-uniform address -> one-line broadcast, L1-resident). Pairs are
// even-aligned subregisters of the b128 loads -> f32x2 chains with zero
// packing movs. Per (query, 2 targets): 3 pk-fma + 1 min3 = 2 insts/pair.
// grid: x = NJT (32), y = B (8), z = dir (2) -> 512 blocks (2/CU).
__global__ __launch_bounds__(THREADS)
void chamfer_partial_kernel(const float* __restrict__ pred,
                            const float* __restrict__ tgt,
                            const float4* __restrict__ TT,
                            float* __restrict__ part)
{
    const int b   = blockIdx.y;
    const int dir = blockIdx.z;
    const int g   = blockIdx.x;

    const float* Q;
    int qoff;
    if (dir == 0) { Q = pred + (size_t)b * N_SZ * 3; qoff = b * N_SZ; }
    else          { Q = tgt  + (size_t)b * M_SZ * 3; qoff = NQ + b * M_SZ; }

    // Packed strip for this block: JTILE/2 pairs, 2 float4 each.
    const float4* __restrict__ S =
        TT + (size_t)((dir * B_SZ + b) * PAIRS_PER_CLOUD + g * (JTILE / 2)) * 2;

    // 16 queries per thread: negated coords pre-splatted into f32x2 pairs.
    f32x2 qxs[QPT], qys[QPT], qzs[QPT];
    float q2h[QPT], mn[QPT];
#pragma unroll
    for (int k = 0; k < QPT; ++k) {
        const int i = threadIdx.x + k * THREADS;
        float x = Q[i * 3 + 0], y = Q[i * 3 + 1], z = Q[i * 3 + 2];
        qxs[k] = { -x, -x };
        qys[k] = { -y, -y };
        qzs[k] = { -z, -z };
        q2h[k] = 0.5f * (x * x + y * y + z * z);
        mn[k]  = 3.0e38f;
    }

#pragma unroll 4
    for (int jp = 0; jp < JTILE / 2; ++jp) {
        const float4 A  = S[2 * jp];       // x0 x1 y0 y1
        const float4 Bv = S[2 * jp + 1];   // z0 z1 h0 h1
        const f32x2 txx = { A.x,  A.y  };
        const f32x2 tyy = { A.z,  A.w  };
        const f32x2 tzz = { Bv.x, Bv.y };
        const f32x2 thh = { Bv.z, Bv.w };
#pragma unroll
        for (int k = 0; k < QPT; ++k) {
            f32x2 sc = __builtin_elementwise_fma(qzs[k], tzz, thh);
            sc       = __builtin_elementwise_fma(qys[k], tyy, sc);
            sc       = __builtin_elementwise_fma(qxs[k], txx, sc);
            mn[k] = fminf(mn[k], fminf(sc.x, sc.y));   // -> v_min3_f32
        }
    }

    // Fold |q|^2/2 -> partial d^2/2; plain coalesced stores.
    float* pg = part + (size_t)g * TOT + qoff;
#pragma unroll
    for (int k = 0; k < QPT; ++k) {
        pg[threadIdx.x + k * THREADS] = mn[k] + q2h[k];
    }
}

// Phase 2: one query per thread; NJT coalesced independent loads; block sum.
__global__ __launch_bounds__(256)
void chamfer_combine_kernel(const float* __restrict__ part,
                            float* __restrict__ bsum)
{
    const int q = blockIdx.x * 256 + threadIdx.x;
    float m = 3.0e38f;
#pragma unroll
    for (int g = 0; g < NJT; ++g) m = fminf(m, part[(size_t)g * TOT + q]);
    float d = sqrtf(2.0f * fmaxf(m, 0.0f));
#pragma unroll
    for (int off = 32; off > 0; off >>= 1) d += __shfl_down(d, off);
    __shared__ float r[4];
    if ((threadIdx.x & 63) == 0) r[threadIdx.x >> 6] = d;
    __syncthreads();
    if (threadIdx.x == 0) bsum[blockIdx.x] = r[0] + r[1] + r[2] + r[3];
}

// Phase 3: one wave sums the 256 block partials.
__global__ __launch_bounds__(64)
void chamfer_final_kernel(const float* __restrict__ bsum,
                          float* __restrict__ out)
{
    float s = 0.0f;
#pragma unroll
    for (int i = 0; i < NBLK2 / 64; ++i) s += bsum[threadIdx.x + i * 64];
#pragma unroll
    for (int off = 32; off > 0; off >>= 1) s += __shfl_down(s, off);
    // loss = mean(min_p2t) + mean(min_t2p) = (sum of all NN dists)/NQ  (N==M)
    if (threadIdx.x == 0) out[0] = s * (1.0f / (float)NQ);
}

extern "C" void kernel_launch(void* const* d_in, const int* in_sizes, int n_in,
                              void* d_out, int out_size, void* d_ws, size_t ws_size,
                              hipStream_t stream) {
    const float* pred = (const float*)d_in[0];  // [B,N,3]
    const float* tgt  = (const float*)d_in[1];  // [B,M,3]
    float* out = (float*)d_out;

    float*  part = (float*)d_ws;                        // NJT*TOT floats = 8 MB
    float*  bsum = part + (size_t)NJT * TOT;            // NBLK2 floats
    float4* TT   = (float4*)(bsum + NBLK2);             // 1 MB packed targets

    chamfer_pack_kernel<<<(2 * B_SZ * PAIRS_PER_CLOUD) / 256, 256, 0, stream>>>(
        pred, tgt, TT);

    dim3 grid1(NJT, B_SZ, 2);
    chamfer_partial_kernel<<<grid1, THREADS, 0, stream>>>(pred, tgt, TT, part);
    chamfer_combine_kernel<<<NBLK2, 256, 0, stream>>>(part, bsum);
    chamfer_final_kernel<<<1, 64, 0, stream>>>(bsum, out);
}